// Round 4
// baseline (613.066 us; speedup 1.0000x reference)
//
#include <hip/hip_runtime.h>
#include <hip/hip_bf16.h>
#include <math.h>

#define BB 2
#define TT 1024
#define CC 768
#define HH 3072
#define NEXP 8
#define NTOK (BB*TT)        // 2048 tokens
#define CAP 1024            // per-expert slab capacity (mean 512, sigma ~20)

typedef __attribute__((ext_vector_type(8))) short short8;
typedef __attribute__((ext_vector_type(4))) float float4v;

// ---------- helpers ----------
__device__ __forceinline__ unsigned short f2bf(float f) {
    unsigned int u = __float_as_uint(f);
    unsigned int r = (u + 0x7fffu + ((u >> 16) & 1u)) >> 16;
    return (unsigned short)r;
}
__device__ __forceinline__ float gelu_tanh(float v) {
    const float k2 = 2.0f * 0.7978845608028654f;
    const float k1 = 0.044715f;
    float z = k2 * (v + k1 * v * v * v);
    return v / (1.0f + __expf(-z));
}

// ---------- router ----------
__global__ void router_kernel(const float* __restrict__ x,
                              const float* __restrict__ w_gate,
                              float* __restrict__ top_p,
                              int* __restrict__ counts,
                              int* __restrict__ tok_list) {
    int t = blockIdx.x;
    int lane = threadIdx.x;
    float acc[NEXP];
#pragma unroll
    for (int e = 0; e < NEXP; ++e) acc[e] = 0.f;
    for (int c = lane; c < CC; c += 64) {
        float xv = x[t * CC + c];
        const float4* wg = (const float4*)(w_gate + c * NEXP);
        float4 w0 = wg[0], w1 = wg[1];
        acc[0] += xv * w0.x; acc[1] += xv * w0.y;
        acc[2] += xv * w0.z; acc[3] += xv * w0.w;
        acc[4] += xv * w1.x; acc[5] += xv * w1.y;
        acc[6] += xv * w1.z; acc[7] += xv * w1.w;
    }
#pragma unroll
    for (int e = 0; e < NEXP; ++e) {
        for (int off = 32; off > 0; off >>= 1)
            acc[e] += __shfl_down(acc[e], off, 64);
    }
    if (lane == 0) {
        float m = acc[0];
#pragma unroll
        for (int e = 1; e < NEXP; ++e) m = fmaxf(m, acc[e]);
        float p[NEXP]; float s = 0.f;
#pragma unroll
        for (int e = 0; e < NEXP; ++e) { p[e] = expf(acc[e] - m); s += p[e]; }
        float inv_s = 1.f / s;
#pragma unroll
        for (int e = 0; e < NEXP; ++e) p[e] *= inv_s;
        int i0 = 0;
#pragma unroll
        for (int e = 1; e < NEXP; ++e) if (p[e] > p[i0]) i0 = e;
        int i1 = (i0 == 0) ? 1 : 0;
#pragma unroll
        for (int e = 0; e < NEXP; ++e) if (e != i0 && p[e] > p[i1]) i1 = e;
        float p0 = p[i0], p1 = p[i1];
        float inv = 1.f / (p0 + p1);
        top_p[t * 2 + 0] = p0 * inv;
        top_p[t * 2 + 1] = p1 * inv;
        int pos0 = atomicAdd(&counts[i0], 1);
        if (pos0 < CAP) tok_list[i0 * NTOK + pos0] = t * 2 + 0;
        int pos1 = atomicAdd(&counts[i1], 1);
        if (pos1 < CAP) tok_list[i1 * NTOK + pos1] = t * 2 + 1;
    }
}

// ---------- weight permute: In[a][b*8+e] fp32 -> Out[e][b][a] bf16 ----------
__global__ __launch_bounds__(256)
void permute_w(const float* __restrict__ In, unsigned short* __restrict__ Out,
               int Adim, int Bdim) {
    __shared__ unsigned short L[32 * 256];
    int a0 = blockIdx.x * 32, b0 = blockIdx.y * 32;
    int t = threadIdx.x;
#pragma unroll
    for (int j = 0; j < 8; ++j) {
        int idx = j * 256 + t;
        int ar = idx >> 6;
        int wi = idx & 63;
        const float4 v = *(const float4*)(In + (size_t)(a0 + ar) * Bdim * 8 + b0 * 8 + wi * 4);
        ushort4 s;
        s.x = f2bf(v.x); s.y = f2bf(v.y); s.z = f2bf(v.z); s.w = f2bf(v.w);
        *(ushort4*)&L[ar * 256 + wi * 4] = s;
    }
    __syncthreads();
    unsigned short tmp[32];
#pragma unroll
    for (int a = 0; a < 32; ++a) tmp[a] = L[a * 256 + t];
    int b = b0 + (t >> 3), e = t & 7;
    unsigned short* dst = Out + ((size_t)e * Bdim + b) * Adim + a0;
#pragma unroll
    for (int j = 0; j < 8; ++j) {
        ushort4 s; s.x = tmp[j*4+0]; s.y = tmp[j*4+1]; s.z = tmp[j*4+2]; s.w = tmp[j*4+3];
        *(ushort4*)(dst + j * 4) = s;
    }
}

// ---------- gather x into per-expert bf16 slabs (zero pad rows) ----------
__global__ void gather_x(const float* __restrict__ x,
                         const int* __restrict__ counts,
                         const int* __restrict__ tok_list,
                         unsigned short* __restrict__ xg) {
    int pos = blockIdx.x;
    int e = pos >> 10, i = pos & (CAP - 1);
    int M = counts[e]; if (M > CAP) M = CAP;
    int Mr = (M + 127) & ~127; if (Mr > CAP) Mr = CAP;
    if (i >= Mr) return;
    int c = threadIdx.x * 4;
    unsigned short* dst = xg + (size_t)pos * CC + c;
    ushort4 s;
    if (i < M) {
        int tk = tok_list[e * NTOK + i] >> 1;
        float4 v = *(const float4*)(x + (size_t)tk * CC + c);
        s.x = f2bf(v.x); s.y = f2bf(v.y); s.z = f2bf(v.z); s.w = f2bf(v.w);
    } else {
        s.x = s.y = s.z = s.w = 0;
    }
    *(ushort4*)dst = s;
}

// ---------- MFMA GEMM1: register-staged pipeline, BK=128 ----------
// A: xg [e][CAP][CC]. B: wfc_b [e][HH][CC]. Out: h_slab [e][CAP][HH] bf16 gelu.
// __launch_bounds__(256,2): cap at 2 waves/EU so ~180 live regs fit w/o spill.
__global__ __launch_bounds__(256, 2)
void gemm1_mfma(const unsigned short* __restrict__ xg,
                const unsigned short* __restrict__ wfc_b,
                const int* __restrict__ counts,
                unsigned short* __restrict__ h_slab) {
    int e = blockIdx.z;
    int M = counts[e]; if (M > CAP) M = CAP;
    int m0 = blockIdx.y * 128;
    if (m0 >= M) return;
    int n0 = blockIdx.x * 128;

    __shared__ unsigned short As[128 * 128];   // 32 KB, row-major [row][k]
    __shared__ unsigned short Bs[128 * 128];

    int tid = threadIdx.x;
    int wave = tid >> 6, lane = tid & 63;
    int wm = wave >> 1, wn = wave & 1;
    int quad = lane >> 4, l16 = lane & 15;

    int sr = tid >> 1;          // staging row 0..127
    int sh = tid & 1;           // k-half: 64 ushorts (8 chunks of 16B)
    const unsigned short* aPtr = xg    + ((size_t)e * CAP + m0 + sr) * CC + sh * 64;
    const unsigned short* bPtr = wfc_b + ((size_t)e * HH  + n0 + sr) * CC + sh * 64;
    unsigned short* aLds = As + sr * 128 + sh * 64;
    unsigned short* bLds = Bs + sr * 128 + sh * 64;

    float4 pa[8], pb[8];
#pragma unroll
    for (int c = 0; c < 8; ++c) {
        pa[c] = *(const float4*)(aPtr + c * 8);
        pb[c] = *(const float4*)(bPtr + c * 8);
    }

    float4v acc[4][4];
#pragma unroll
    for (int i = 0; i < 4; ++i)
#pragma unroll
        for (int j = 0; j < 4; ++j)
#pragma unroll
            for (int r = 0; r < 4; ++r) acc[i][j][r] = 0.f;

    for (int k0 = 0; k0 < CC; k0 += 128) {
        __syncthreads();
#pragma unroll
        for (int c = 0; c < 8; ++c) {
            *(float4*)(aLds + c * 8) = pa[c];
            *(float4*)(bLds + c * 8) = pb[c];
        }
        __syncthreads();
        if (k0 + 128 < CC) {
            aPtr += 128; bPtr += 128;
#pragma unroll
            for (int c = 0; c < 8; ++c) {
                pa[c] = *(const float4*)(aPtr + c * 8);
                pb[c] = *(const float4*)(bPtr + c * 8);
            }
        }
#pragma unroll
        for (int s = 0; s < 4; ++s) {
            short8 af[4], bf[4];
#pragma unroll
            for (int mt = 0; mt < 4; ++mt)
                af[mt] = *(const short8*)&As[(wm * 64 + mt * 16 + l16) * 128 + s * 32 + quad * 8];
#pragma unroll
            for (int nt = 0; nt < 4; ++nt)
                bf[nt] = *(const short8*)&Bs[(wn * 64 + nt * 16 + l16) * 128 + s * 32 + quad * 8];
#pragma unroll
            for (int mt = 0; mt < 4; ++mt)
#pragma unroll
                for (int nt = 0; nt < 4; ++nt)
                    acc[mt][nt] = __builtin_amdgcn_mfma_f32_16x16x32_bf16(
                        af[mt], bf[nt], acc[mt][nt], 0, 0, 0);
        }
    }

#pragma unroll
    for (int mt = 0; mt < 4; ++mt) {
#pragma unroll
        for (int r = 0; r < 4; ++r) {
            int m = m0 + wm * 64 + mt * 16 + quad * 4 + r;
            unsigned short* orow = h_slab + ((size_t)e * CAP + m) * HH + n0 + wn * 64 + l16;
#pragma unroll
            for (int nt = 0; nt < 4; ++nt)
                orow[nt * 16] = f2bf(gelu_tanh(acc[mt][nt][r]));
        }
    }
}

// ---------- MFMA GEMM2: register-staged, BK=128, split-K=4, no atomics ----------
// A: h_slab [e][CAP][HH]. B: wp_b [e][CC][HH]. Out: o_part[ks][ent][CC] fp32.
__global__ __launch_bounds__(256, 2)
void gemm2_mfma(const unsigned short* __restrict__ h_slab,
                const unsigned short* __restrict__ wp_b,
                const int* __restrict__ counts,
                const int* __restrict__ tok_list,
                float* __restrict__ o_part) {
    int e = blockIdx.z;
    int M = counts[e]; if (M > CAP) M = CAP;
    int m0 = blockIdx.y * 128;
    if (m0 >= M) return;
    int n0 = (blockIdx.x >> 2) * 128;
    int ks = blockIdx.x & 3;

    __shared__ unsigned short As[128 * 128];
    __shared__ unsigned short Bs[128 * 128];

    int tid = threadIdx.x;
    int wave = tid >> 6, lane = tid & 63;
    int wm = wave >> 1, wn = wave & 1;
    int quad = lane >> 4, l16 = lane & 15;

    int sr = tid >> 1;
    int sh = tid & 1;
    const unsigned short* aPtr = h_slab + ((size_t)e * CAP + m0 + sr) * HH + ks * 768 + sh * 64;
    const unsigned short* bPtr = wp_b   + ((size_t)e * CC  + n0 + sr) * HH + ks * 768 + sh * 64;
    unsigned short* aLds = As + sr * 128 + sh * 64;
    unsigned short* bLds = Bs + sr * 128 + sh * 64;

    float4 pa[8], pb[8];
#pragma unroll
    for (int c = 0; c < 8; ++c) {
        pa[c] = *(const float4*)(aPtr + c * 8);
        pb[c] = *(const float4*)(bPtr + c * 8);
    }

    float4v acc[4][4];
#pragma unroll
    for (int i = 0; i < 4; ++i)
#pragma unroll
        for (int j = 0; j < 4; ++j)
#pragma unroll
            for (int r = 0; r < 4; ++r) acc[i][j][r] = 0.f;

    for (int k0 = 0; k0 < 768; k0 += 128) {
        __syncthreads();
#pragma unroll
        for (int c = 0; c < 8; ++c) {
            *(float4*)(aLds + c * 8) = pa[c];
            *(float4*)(bLds + c * 8) = pb[c];
        }
        __syncthreads();
        if (k0 + 128 < 768) {
            aPtr += 128; bPtr += 128;
#pragma unroll
            for (int c = 0; c < 8; ++c) {
                pa[c] = *(const float4*)(aPtr + c * 8);
                pb[c] = *(const float4*)(bPtr + c * 8);
            }
        }
#pragma unroll
        for (int s = 0; s < 4; ++s) {
            short8 af[4], bf[4];
#pragma unroll
            for (int mt = 0; mt < 4; ++mt)
                af[mt] = *(const short8*)&As[(wm * 64 + mt * 16 + l16) * 128 + s * 32 + quad * 8];
#pragma unroll
            for (int nt = 0; nt < 4; ++nt)
                bf[nt] = *(const short8*)&Bs[(wn * 64 + nt * 16 + l16) * 128 + s * 32 + quad * 8];
#pragma unroll
            for (int mt = 0; mt < 4; ++mt)
#pragma unroll
                for (int nt = 0; nt < 4; ++nt)
                    acc[mt][nt] = __builtin_amdgcn_mfma_f32_16x16x32_bf16(
                        af[mt], bf[nt], acc[mt][nt], 0, 0, 0);
        }
    }

#pragma unroll
    for (int mt = 0; mt < 4; ++mt) {
#pragma unroll
        for (int r = 0; r < 4; ++r) {
            int m = m0 + wm * 64 + mt * 16 + quad * 4 + r;
            if (m < M) {
                int ent = tok_list[e * NTOK + m];
                float* orow = o_part + ((size_t)ks * NTOK * 2 + ent) * CC + n0 + wn * 64 + l16;
#pragma unroll
                for (int nt = 0; nt < 4; ++nt)
                    orow[nt * 16] = acc[mt][nt][r];
            }
        }
    }
}

// ---------- combine: out[t] = sum_k p_k * sum_ks o_part[ks][2t+k] ----------
__global__ void combine_kernel(const float* __restrict__ o_part,
                               const float* __restrict__ top_p,
                               float* __restrict__ out) {
    int idx = blockIdx.x * 256 + threadIdx.x;
    int t = idx / (CC / 4);
    int c = (idx % (CC / 4)) * 4;
    float p0 = top_p[2 * t], p1 = top_p[2 * t + 1];
    float4 s0 = make_float4(0.f, 0.f, 0.f, 0.f);
    float4 s1 = make_float4(0.f, 0.f, 0.f, 0.f);
#pragma unroll
    for (int ks = 0; ks < 4; ++ks) {
        const float4 a = *(const float4*)(o_part + ((size_t)ks * NTOK * 2 + 2 * t) * CC + c);
        const float4 b = *(const float4*)(o_part + ((size_t)ks * NTOK * 2 + 2 * t + 1) * CC + c);
        s0.x += a.x; s0.y += a.y; s0.z += a.z; s0.w += a.w;
        s1.x += b.x; s1.y += b.y; s1.z += b.z; s1.w += b.w;
    }
    float4 r;
    r.x = p0 * s0.x + p1 * s1.x;
    r.y = p0 * s0.y + p1 * s1.y;
    r.z = p0 * s0.z + p1 * s1.z;
    r.w = p0 * s0.w + p1 * s1.w;
    *(float4*)(out + (size_t)t * CC + c) = r;
}

// ---------- launch ----------
extern "C" void kernel_launch(void* const* d_in, const int* in_sizes, int n_in,
                              void* d_out, int out_size, void* d_ws, size_t ws_size,
                              hipStream_t stream) {
    const float* x      = (const float*)d_in[0];
    const float* w_fc   = (const float*)d_in[1];
    const float* w_proj = (const float*)d_in[2];
    const float* w_gate = (const float*)d_in[3];
    float* out = (float*)d_out;

    char* ws = (char*)d_ws;
    size_t off = 0;
    float* top_p    = (float*)(ws + off); off += NTOK * 2 * sizeof(float);
    int*   counts   = (int*)(ws + off);   off += 256;
    int*   tok_list = (int*)(ws + off);   off += (size_t)NEXP * NTOK * 4;
    off = 131072;
    unsigned short* wp_b   = (unsigned short*)(ws + off); off += (size_t)NEXP*CC*HH*2;  // 37.75 MB
    unsigned short* h_slab = (unsigned short*)(ws + off); off += (size_t)NEXP*CAP*HH*2; // 50.33 MB
    // o_part aliases [wfc_b][xg] (both dead once gemm1 completes; stream order
    // serializes). sizeof(o_part) = 4*4096*768*4 = 50,331,648 == wfc_b + xg.
    unsigned short* wfc_b  = (unsigned short*)(ws + off);
    float*          o_part = (float*)(ws + off);          off += (size_t)NEXP*HH*CC*2;  // 37.75 MB
    unsigned short* xg     = (unsigned short*)(ws + off); off += (size_t)NEXP*CAP*CC*2; // 12.58 MB

    hipMemsetAsync(counts, 0, 256, stream);

    router_kernel<<<NTOK, 64, 0, stream>>>(x, w_gate, top_p, counts, tok_list);
    permute_w<<<dim3(CC / 32, HH / 32), 256, 0, stream>>>(w_fc, wfc_b, CC, HH);
    permute_w<<<dim3(HH / 32, CC / 32), 256, 0, stream>>>(w_proj, wp_b, HH, CC);
    gather_x<<<NEXP * CAP, 192, 0, stream>>>(x, counts, tok_list, xg);

    gemm1_mfma<<<dim3(HH / 128, CAP / 128, NEXP), 256, 0, stream>>>(
        xg, wfc_b, counts, h_slab);
    gemm2_mfma<<<dim3((CC / 128) * 4, CAP / 128, NEXP), 256, 0, stream>>>(
        h_slab, wp_b, counts, tok_list, o_part);
    combine_kernel<<<(NTOK * CC / 4) / 256, 256, 0, stream>>>(o_part, top_p, out);
}

// Round 5
// 352.438 us; speedup vs baseline: 1.7395x; 1.7395x over previous
//
#include <hip/hip_runtime.h>
#include <hip/hip_bf16.h>
#include <math.h>

#define BB 2
#define TT 1024
#define CC 768
#define HH 3072
#define NEXP 8
#define NTOK (BB*TT)        // 2048 tokens
#define CAP 1024            // per-expert slab capacity (mean 512, sigma ~20)

typedef __attribute__((ext_vector_type(8))) short short8;
typedef __attribute__((ext_vector_type(4))) float float4v;

typedef const __attribute__((address_space(1))) void* gptr_t;
typedef __attribute__((address_space(3))) void* sptr_t;

// ---------- helpers ----------
__device__ __forceinline__ unsigned short f2bf(float f) {
    unsigned int u = __float_as_uint(f);
    unsigned int r = (u + 0x7fffu + ((u >> 16) & 1u)) >> 16;
    return (unsigned short)r;
}
__device__ __forceinline__ float gelu_tanh(float v) {
    const float k2 = 2.0f * 0.7978845608028654f;
    const float k1 = 0.044715f;
    float z = k2 * (v + k1 * v * v * v);
    return v / (1.0f + __expf(-z));
}

// ---------- router ----------
__global__ void router_kernel(const float* __restrict__ x,
                              const float* __restrict__ w_gate,
                              float* __restrict__ top_p,
                              int* __restrict__ counts,
                              int* __restrict__ tok_list) {
    int t = blockIdx.x;
    int lane = threadIdx.x;
    float acc[NEXP];
#pragma unroll
    for (int e = 0; e < NEXP; ++e) acc[e] = 0.f;
    for (int c = lane; c < CC; c += 64) {
        float xv = x[t * CC + c];
        const float4* wg = (const float4*)(w_gate + c * NEXP);
        float4 w0 = wg[0], w1 = wg[1];
        acc[0] += xv * w0.x; acc[1] += xv * w0.y;
        acc[2] += xv * w0.z; acc[3] += xv * w0.w;
        acc[4] += xv * w1.x; acc[5] += xv * w1.y;
        acc[6] += xv * w1.z; acc[7] += xv * w1.w;
    }
#pragma unroll
    for (int e = 0; e < NEXP; ++e) {
        for (int off = 32; off > 0; off >>= 1)
            acc[e] += __shfl_down(acc[e], off, 64);
    }
    if (lane == 0) {
        float m = acc[0];
#pragma unroll
        for (int e = 1; e < NEXP; ++e) m = fmaxf(m, acc[e]);
        float p[NEXP]; float s = 0.f;
#pragma unroll
        for (int e = 0; e < NEXP; ++e) { p[e] = expf(acc[e] - m); s += p[e]; }
        float inv_s = 1.f / s;
#pragma unroll
        for (int e = 0; e < NEXP; ++e) p[e] *= inv_s;
        int i0 = 0;
#pragma unroll
        for (int e = 1; e < NEXP; ++e) if (p[e] > p[i0]) i0 = e;
        int i1 = (i0 == 0) ? 1 : 0;
#pragma unroll
        for (int e = 0; e < NEXP; ++e) if (e != i0 && p[e] > p[i1]) i1 = e;
        float p0 = p[i0], p1 = p[i1];
        float inv = 1.f / (p0 + p1);
        top_p[t * 2 + 0] = p0 * inv;
        top_p[t * 2 + 1] = p1 * inv;
        int pos0 = atomicAdd(&counts[i0], 1);
        if (pos0 < CAP) tok_list[i0 * NTOK + pos0] = t * 2 + 0;
        int pos1 = atomicAdd(&counts[i1], 1);
        if (pos1 < CAP) tok_list[i1 * NTOK + pos1] = t * 2 + 1;
    }
}

// ---------- weight permute: In[a][b*8+e] fp32 -> Out[e][b][a] bf16 ----------
__global__ __launch_bounds__(256)
void permute_w(const float* __restrict__ In, unsigned short* __restrict__ Out,
               int Adim, int Bdim) {
    __shared__ unsigned short L[32 * 256];
    int a0 = blockIdx.x * 32, b0 = blockIdx.y * 32;
    int t = threadIdx.x;
#pragma unroll
    for (int j = 0; j < 8; ++j) {
        int idx = j * 256 + t;
        int ar = idx >> 6;
        int wi = idx & 63;
        const float4 v = *(const float4*)(In + (size_t)(a0 + ar) * Bdim * 8 + b0 * 8 + wi * 4);
        ushort4 s;
        s.x = f2bf(v.x); s.y = f2bf(v.y); s.z = f2bf(v.z); s.w = f2bf(v.w);
        *(ushort4*)&L[ar * 256 + wi * 4] = s;
    }
    __syncthreads();
    unsigned short tmp[32];
#pragma unroll
    for (int a = 0; a < 32; ++a) tmp[a] = L[a * 256 + t];
    int b = b0 + (t >> 3), e = t & 7;
    unsigned short* dst = Out + ((size_t)e * Bdim + b) * Adim + a0;
#pragma unroll
    for (int j = 0; j < 8; ++j) {
        ushort4 s; s.x = tmp[j*4+0]; s.y = tmp[j*4+1]; s.z = tmp[j*4+2]; s.w = tmp[j*4+3];
        *(ushort4*)(dst + j * 4) = s;
    }
}

// ---------- gather x into per-expert bf16 slabs (zero pad rows) ----------
__global__ void gather_x(const float* __restrict__ x,
                         const int* __restrict__ counts,
                         const int* __restrict__ tok_list,
                         unsigned short* __restrict__ xg) {
    int pos = blockIdx.x;
    int e = pos >> 10, i = pos & (CAP - 1);
    int M = counts[e]; if (M > CAP) M = CAP;
    int Mr = (M + 127) & ~127; if (Mr > CAP) Mr = CAP;
    if (i >= Mr) return;
    int c = threadIdx.x * 4;
    unsigned short* dst = xg + (size_t)pos * CC + c;
    ushort4 s;
    if (i < M) {
        int tk = tok_list[e * NTOK + i] >> 1;
        float4 v = *(const float4*)(x + (size_t)tk * CC + c);
        s.x = f2bf(v.x); s.y = f2bf(v.y); s.z = f2bf(v.z); s.w = f2bf(v.w);
    } else {
        s.x = s.y = s.z = s.w = 0;
    }
    *(ushort4*)dst = s;
}

// ---------- MFMA GEMM1: double-buffered global_load_lds, BK=32 ----------
// A: xg [e][CAP][CC]. B: wfc_b [e][HH][CC]. Out: h_slab [e][CAP][HH] bf16 gelu.
// One barrier per K-iter: barrier (drains prev-iter DMA) -> issue DMA into
// other buffer -> compute current. Load latency overlaps compute.
__global__ __launch_bounds__(256)
void gemm1_mfma(const unsigned short* __restrict__ xg,
                const unsigned short* __restrict__ wfc_b,
                const int* __restrict__ counts,
                unsigned short* __restrict__ h_slab) {
    int e = blockIdx.z;
    int M = counts[e]; if (M > CAP) M = CAP;
    int m0 = blockIdx.y * 128;
    if (m0 >= M) return;
    int n0 = blockIdx.x * 128;

    __shared__ unsigned short As[2][128 * 32];
    __shared__ unsigned short Bs[2][128 * 32];

    int tid = threadIdx.x;
    int wave = tid >> 6, lane = tid & 63;
    int wm = wave >> 1, wn = wave & 1;
    int quad = lane >> 4, l16 = lane & 15;

    const unsigned short* aBase = xg + ((size_t)e * CAP + m0) * CC;
    const unsigned short* bBase = wfc_b + ((size_t)e * HH + n0) * CC;

    int srow = wave * 32 + (lane >> 2);   // row this lane stages (q=0)
    int schunk = (lane & 3) * 8;          // 16B chunk within the 32-ushort row

    float4v acc[4][4];
#pragma unroll
    for (int i = 0; i < 4; ++i)
#pragma unroll
        for (int j = 0; j < 4; ++j)
#pragma unroll
            for (int r = 0; r < 4; ++r) acc[i][j][r] = 0.f;

    // prologue: stage k0=0 into buffer 0
#pragma unroll
    for (int q = 0; q < 2; ++q) {
        int r = srow + q * 16;
        __builtin_amdgcn_global_load_lds(
            (gptr_t)(aBase + (size_t)r * CC + schunk),
            (sptr_t)(&As[0][(wave * 32 + q * 16) * 32]), 16, 0, 0);
        __builtin_amdgcn_global_load_lds(
            (gptr_t)(bBase + (size_t)r * CC + schunk),
            (sptr_t)(&Bs[0][(wave * 32 + q * 16) * 32]), 16, 0, 0);
    }

    for (int k0 = 0; k0 < CC; k0 += 32) {
        int cur = (k0 >> 5) & 1;
        __syncthreads();   // per-wave vmcnt(0) drain => buf[cur] resident for all
        if (k0 + 32 < CC) {
            int nxt = cur ^ 1;
#pragma unroll
            for (int q = 0; q < 2; ++q) {
                int r = srow + q * 16;
                __builtin_amdgcn_global_load_lds(
                    (gptr_t)(aBase + (size_t)r * CC + k0 + 32 + schunk),
                    (sptr_t)(&As[nxt][(wave * 32 + q * 16) * 32]), 16, 0, 0);
                __builtin_amdgcn_global_load_lds(
                    (gptr_t)(bBase + (size_t)r * CC + k0 + 32 + schunk),
                    (sptr_t)(&Bs[nxt][(wave * 32 + q * 16) * 32]), 16, 0, 0);
            }
        }
        short8 af[4], bf[4];
#pragma unroll
        for (int mt = 0; mt < 4; ++mt)
            af[mt] = *(const short8*)&As[cur][(wm * 64 + mt * 16 + l16) * 32 + quad * 8];
#pragma unroll
        for (int nt = 0; nt < 4; ++nt)
            bf[nt] = *(const short8*)&Bs[cur][(wn * 64 + nt * 16 + l16) * 32 + quad * 8];
#pragma unroll
        for (int mt = 0; mt < 4; ++mt)
#pragma unroll
            for (int nt = 0; nt < 4; ++nt)
                acc[mt][nt] = __builtin_amdgcn_mfma_f32_16x16x32_bf16(
                    af[mt], bf[nt], acc[mt][nt], 0, 0, 0);
    }

    // epilogue: gelu -> bf16 (pad rows get gelu(0)=0; gemm2 reads them as zeros)
#pragma unroll
    for (int mt = 0; mt < 4; ++mt) {
#pragma unroll
        for (int r = 0; r < 4; ++r) {
            int m = m0 + wm * 64 + mt * 16 + quad * 4 + r;
            unsigned short* orow = h_slab + ((size_t)e * CAP + m) * HH + n0 + wn * 64 + l16;
#pragma unroll
            for (int nt = 0; nt < 4; ++nt)
                orow[nt * 16] = f2bf(gelu_tanh(acc[mt][nt][r]));
        }
    }
}

// ---------- MFMA GEMM2: double-buffered, BK=32, split-K=4, no atomics ----------
// A: h_slab [e][CAP][HH]. B: wp_b [e][CC][HH]. Out: o_part[ks][ent][CC] fp32.
__global__ __launch_bounds__(256)
void gemm2_mfma(const unsigned short* __restrict__ h_slab,
                const unsigned short* __restrict__ wp_b,
                const int* __restrict__ counts,
                const int* __restrict__ tok_list,
                float* __restrict__ o_part) {
    int e = blockIdx.z;
    int M = counts[e]; if (M > CAP) M = CAP;
    int m0 = blockIdx.y * 128;
    if (m0 >= M) return;
    int n0 = (blockIdx.x >> 2) * 128;
    int ks = blockIdx.x & 3;

    __shared__ unsigned short As[2][128 * 32];
    __shared__ unsigned short Bs[2][128 * 32];

    int tid = threadIdx.x;
    int wave = tid >> 6, lane = tid & 63;
    int wm = wave >> 1, wn = wave & 1;
    int quad = lane >> 4, l16 = lane & 15;

    const unsigned short* aBase = h_slab + ((size_t)e * CAP + m0) * HH + ks * 768;
    const unsigned short* bBase = wp_b + ((size_t)e * CC + n0) * HH + ks * 768;

    int srow = wave * 32 + (lane >> 2);
    int schunk = (lane & 3) * 8;

    float4v acc[4][4];
#pragma unroll
    for (int i = 0; i < 4; ++i)
#pragma unroll
        for (int j = 0; j < 4; ++j)
#pragma unroll
            for (int r = 0; r < 4; ++r) acc[i][j][r] = 0.f;

#pragma unroll
    for (int q = 0; q < 2; ++q) {
        int r = srow + q * 16;
        __builtin_amdgcn_global_load_lds(
            (gptr_t)(aBase + (size_t)r * HH + schunk),
            (sptr_t)(&As[0][(wave * 32 + q * 16) * 32]), 16, 0, 0);
        __builtin_amdgcn_global_load_lds(
            (gptr_t)(bBase + (size_t)r * HH + schunk),
            (sptr_t)(&Bs[0][(wave * 32 + q * 16) * 32]), 16, 0, 0);
    }

    for (int k0 = 0; k0 < 768; k0 += 32) {
        int cur = (k0 >> 5) & 1;
        __syncthreads();
        if (k0 + 32 < 768) {
            int nxt = cur ^ 1;
#pragma unroll
            for (int q = 0; q < 2; ++q) {
                int r = srow + q * 16;
                __builtin_amdgcn_global_load_lds(
                    (gptr_t)(aBase + (size_t)r * HH + k0 + 32 + schunk),
                    (sptr_t)(&As[nxt][(wave * 32 + q * 16) * 32]), 16, 0, 0);
                __builtin_amdgcn_global_load_lds(
                    (gptr_t)(bBase + (size_t)r * HH + k0 + 32 + schunk),
                    (sptr_t)(&Bs[nxt][(wave * 32 + q * 16) * 32]), 16, 0, 0);
            }
        }
        short8 af[4], bf[4];
#pragma unroll
        for (int mt = 0; mt < 4; ++mt)
            af[mt] = *(const short8*)&As[cur][(wm * 64 + mt * 16 + l16) * 32 + quad * 8];
#pragma unroll
        for (int nt = 0; nt < 4; ++nt)
            bf[nt] = *(const short8*)&Bs[cur][(wn * 64 + nt * 16 + l16) * 32 + quad * 8];
#pragma unroll
        for (int mt = 0; mt < 4; ++mt)
#pragma unroll
            for (int nt = 0; nt < 4; ++nt)
                acc[mt][nt] = __builtin_amdgcn_mfma_f32_16x16x32_bf16(
                    af[mt], bf[nt], acc[mt][nt], 0, 0, 0);
    }

#pragma unroll
    for (int mt = 0; mt < 4; ++mt) {
#pragma unroll
        for (int r = 0; r < 4; ++r) {
            int m = m0 + wm * 64 + mt * 16 + quad * 4 + r;
            if (m < M) {
                int ent = tok_list[e * NTOK + m];
                float* orow = o_part + ((size_t)ks * NTOK * 2 + ent) * CC + n0 + wn * 64 + l16;
#pragma unroll
                for (int nt = 0; nt < 4; ++nt)
                    orow[nt * 16] = acc[mt][nt][r];
            }
        }
    }
}

// ---------- combine: out[t] = sum_k p_k * sum_ks o_part[ks][2t+k] ----------
__global__ void combine_kernel(const float* __restrict__ o_part,
                               const float* __restrict__ top_p,
                               float* __restrict__ out) {
    int idx = blockIdx.x * 256 + threadIdx.x;
    int t = idx / (CC / 4);
    int c = (idx % (CC / 4)) * 4;
    float p0 = top_p[2 * t], p1 = top_p[2 * t + 1];
    float4 s0 = make_float4(0.f, 0.f, 0.f, 0.f);
    float4 s1 = make_float4(0.f, 0.f, 0.f, 0.f);
#pragma unroll
    for (int ks = 0; ks < 4; ++ks) {
        const float4 a = *(const float4*)(o_part + ((size_t)ks * NTOK * 2 + 2 * t) * CC + c);
        const float4 b = *(const float4*)(o_part + ((size_t)ks * NTOK * 2 + 2 * t + 1) * CC + c);
        s0.x += a.x; s0.y += a.y; s0.z += a.z; s0.w += a.w;
        s1.x += b.x; s1.y += b.y; s1.z += b.z; s1.w += b.w;
    }
    float4 r;
    r.x = p0 * s0.x + p1 * s1.x;
    r.y = p0 * s0.y + p1 * s1.y;
    r.z = p0 * s0.z + p1 * s1.z;
    r.w = p0 * s0.w + p1 * s1.w;
    *(float4*)(out + (size_t)t * CC + c) = r;
}

// ---------- launch ----------
extern "C" void kernel_launch(void* const* d_in, const int* in_sizes, int n_in,
                              void* d_out, int out_size, void* d_ws, size_t ws_size,
                              hipStream_t stream) {
    const float* x      = (const float*)d_in[0];
    const float* w_fc   = (const float*)d_in[1];
    const float* w_proj = (const float*)d_in[2];
    const float* w_gate = (const float*)d_in[3];
    float* out = (float*)d_out;

    char* ws = (char*)d_ws;
    size_t off = 0;
    float* top_p    = (float*)(ws + off); off += NTOK * 2 * sizeof(float);
    int*   counts   = (int*)(ws + off);   off += 256;
    int*   tok_list = (int*)(ws + off);   off += (size_t)NEXP * NTOK * 4;
    off = 131072;
    unsigned short* wp_b   = (unsigned short*)(ws + off); off += (size_t)NEXP*CC*HH*2;  // 37.75 MB
    unsigned short* h_slab = (unsigned short*)(ws + off); off += (size_t)NEXP*CAP*HH*2; // 50.33 MB
    // o_part aliases [wfc_b][xg] (both dead once gemm1 completes; stream order
    // serializes). sizeof(o_part) = 4*4096*768*4 = 50,331,648 == wfc_b + xg.
    unsigned short* wfc_b  = (unsigned short*)(ws + off);
    float*          o_part = (float*)(ws + off);          off += (size_t)NEXP*HH*CC*2;  // 37.75 MB
    unsigned short* xg     = (unsigned short*)(ws + off); off += (size_t)NEXP*CAP*CC*2; // 12.58 MB

    hipMemsetAsync(counts, 0, 256, stream);

    router_kernel<<<NTOK, 64, 0, stream>>>(x, w_gate, top_p, counts, tok_list);
    permute_w<<<dim3(CC / 32, HH / 32), 256, 0, stream>>>(w_fc, wfc_b, CC, HH);
    permute_w<<<dim3(HH / 32, CC / 32), 256, 0, stream>>>(w_proj, wp_b, HH, CC);
    gather_x<<<NEXP * CAP, 192, 0, stream>>>(x, counts, tok_list, xg);

    gemm1_mfma<<<dim3(HH / 128, CAP / 128, NEXP), 256, 0, stream>>>(
        xg, wfc_b, counts, h_slab);
    gemm2_mfma<<<dim3((CC / 128) * 4, CAP / 128, NEXP), 256, 0, stream>>>(
        h_slab, wp_b, counts, tok_list, o_part);
    combine_kernel<<<(NTOK * CC / 4) / 256, 256, 0, stream>>>(o_part, top_p, out);
}

// Round 6
// 312.725 us; speedup vs baseline: 1.9604x; 1.1270x over previous
//
#include <hip/hip_runtime.h>
#include <hip/hip_bf16.h>
#include <math.h>

#define BB 2
#define TT 1024
#define CC 768
#define HH 3072
#define NEXP 8
#define NTOK (BB*TT)        // 2048 tokens
#define CAP 1024            // per-expert slab capacity (mean 512, sigma ~20)
#define CNT_STRIDE 32       // ints; pads each expert counter to its own 128-B line

typedef __attribute__((ext_vector_type(8))) short short8;
typedef __attribute__((ext_vector_type(4))) float float4v;

typedef const __attribute__((address_space(1))) void* gptr_t;
typedef __attribute__((address_space(3))) void* sptr_t;

// ---------- helpers ----------
__device__ __forceinline__ unsigned short f2bf(float f) {
    unsigned int u = __float_as_uint(f);
    unsigned int r = (u + 0x7fffu + ((u >> 16) & 1u)) >> 16;
    return (unsigned short)r;
}
__device__ __forceinline__ float gelu_tanh(float v) {
    const float k2 = 2.0f * 0.7978845608028654f;
    const float k1 = 0.044715f;
    float z = k2 * (v + k1 * v * v * v);
    return v / (1.0f + __expf(-z));
}

// ---------- router ----------
__global__ void router_kernel(const float* __restrict__ x,
                              const float* __restrict__ w_gate,
                              float* __restrict__ top_p,
                              int* __restrict__ counts,
                              int* __restrict__ tok_list) {
    int t = blockIdx.x;
    int lane = threadIdx.x;
    float acc[NEXP];
#pragma unroll
    for (int e = 0; e < NEXP; ++e) acc[e] = 0.f;
    for (int c = lane; c < CC; c += 64) {
        float xv = x[t * CC + c];
        const float4* wg = (const float4*)(w_gate + c * NEXP);
        float4 w0 = wg[0], w1 = wg[1];
        acc[0] += xv * w0.x; acc[1] += xv * w0.y;
        acc[2] += xv * w0.z; acc[3] += xv * w0.w;
        acc[4] += xv * w1.x; acc[5] += xv * w1.y;
        acc[6] += xv * w1.z; acc[7] += xv * w1.w;
    }
#pragma unroll
    for (int e = 0; e < NEXP; ++e) {
        for (int off = 32; off > 0; off >>= 1)
            acc[e] += __shfl_down(acc[e], off, 64);
    }
    if (lane == 0) {
        float m = acc[0];
#pragma unroll
        for (int e = 1; e < NEXP; ++e) m = fmaxf(m, acc[e]);
        float p[NEXP]; float s = 0.f;
#pragma unroll
        for (int e = 0; e < NEXP; ++e) { p[e] = expf(acc[e] - m); s += p[e]; }
        float inv_s = 1.f / s;
#pragma unroll
        for (int e = 0; e < NEXP; ++e) p[e] *= inv_s;
        int i0 = 0;
#pragma unroll
        for (int e = 1; e < NEXP; ++e) if (p[e] > p[i0]) i0 = e;
        int i1 = (i0 == 0) ? 1 : 0;
#pragma unroll
        for (int e = 0; e < NEXP; ++e) if (e != i0 && p[e] > p[i1]) i1 = e;
        float p0 = p[i0], p1 = p[i1];
        float inv = 1.f / (p0 + p1);
        top_p[t * 2 + 0] = p0 * inv;
        top_p[t * 2 + 1] = p1 * inv;
        // padded counters: each expert's counter lives in its own 128-B line,
        // so the 4096 device atomics spread over 8 L2 lines instead of one.
        int pos0 = atomicAdd(&counts[i0 * CNT_STRIDE], 1);
        if (pos0 < CAP) tok_list[i0 * NTOK + pos0] = t * 2 + 0;
        int pos1 = atomicAdd(&counts[i1 * CNT_STRIDE], 1);
        if (pos1 < CAP) tok_list[i1 * NTOK + pos1] = t * 2 + 1;
    }
}

// ---------- weight permute: In[a][b*8+e] fp32 -> Out[e][b][a] bf16 ----------
__global__ __launch_bounds__(256)
void permute_w(const float* __restrict__ In, unsigned short* __restrict__ Out,
               int Adim, int Bdim) {
    __shared__ unsigned short L[32 * 256];
    int a0 = blockIdx.x * 32, b0 = blockIdx.y * 32;
    int t = threadIdx.x;
#pragma unroll
    for (int j = 0; j < 8; ++j) {
        int idx = j * 256 + t;
        int ar = idx >> 6;
        int wi = idx & 63;
        const float4 v = *(const float4*)(In + (size_t)(a0 + ar) * Bdim * 8 + b0 * 8 + wi * 4);
        ushort4 s;
        s.x = f2bf(v.x); s.y = f2bf(v.y); s.z = f2bf(v.z); s.w = f2bf(v.w);
        *(ushort4*)&L[ar * 256 + wi * 4] = s;
    }
    __syncthreads();
    unsigned short tmp[32];
#pragma unroll
    for (int a = 0; a < 32; ++a) tmp[a] = L[a * 256 + t];
    int b = b0 + (t >> 3), e = t & 7;
    unsigned short* dst = Out + ((size_t)e * Bdim + b) * Adim + a0;
#pragma unroll
    for (int j = 0; j < 8; ++j) {
        ushort4 s; s.x = tmp[j*4+0]; s.y = tmp[j*4+1]; s.z = tmp[j*4+2]; s.w = tmp[j*4+3];
        *(ushort4*)(dst + j * 4) = s;
    }
}

// ---------- gather x into per-expert bf16 slabs (zero pad rows) ----------
__global__ void gather_x(const float* __restrict__ x,
                         const int* __restrict__ counts,
                         const int* __restrict__ tok_list,
                         unsigned short* __restrict__ xg) {
    int pos = blockIdx.x;
    int e = pos >> 10, i = pos & (CAP - 1);
    int M = counts[e * CNT_STRIDE]; if (M > CAP) M = CAP;
    int Mr = (M + 127) & ~127; if (Mr > CAP) Mr = CAP;
    if (i >= Mr) return;
    int c = threadIdx.x * 4;
    unsigned short* dst = xg + (size_t)pos * CC + c;
    ushort4 s;
    if (i < M) {
        int tk = tok_list[e * NTOK + i] >> 1;
        float4 v = *(const float4*)(x + (size_t)tk * CC + c);
        s.x = f2bf(v.x); s.y = f2bf(v.y); s.z = f2bf(v.z); s.w = f2bf(v.w);
    } else {
        s.x = s.y = s.z = s.w = 0;
    }
    *(ushort4*)dst = s;
}

// ---------- MFMA GEMM1: double-buffered global_load_lds, BK=32 ----------
// A: xg [e][CAP][CC]. B: wfc_b [e][HH][CC]. Out: h_slab [e][CAP][HH] bf16 gelu.
// One barrier per K-iter: barrier (drains prev-iter DMA) -> issue DMA into
// other buffer -> compute current. Load latency overlaps compute.
__global__ __launch_bounds__(256)
void gemm1_mfma(const unsigned short* __restrict__ xg,
                const unsigned short* __restrict__ wfc_b,
                const int* __restrict__ counts,
                unsigned short* __restrict__ h_slab) {
    int e = blockIdx.z;
    int M = counts[e * CNT_STRIDE]; if (M > CAP) M = CAP;
    int m0 = blockIdx.y * 128;
    if (m0 >= M) return;
    int n0 = blockIdx.x * 128;

    __shared__ unsigned short As[2][128 * 32];
    __shared__ unsigned short Bs[2][128 * 32];

    int tid = threadIdx.x;
    int wave = tid >> 6, lane = tid & 63;
    int wm = wave >> 1, wn = wave & 1;
    int quad = lane >> 4, l16 = lane & 15;

    const unsigned short* aBase = xg + ((size_t)e * CAP + m0) * CC;
    const unsigned short* bBase = wfc_b + ((size_t)e * HH + n0) * CC;

    int srow = wave * 32 + (lane >> 2);   // row this lane stages (q=0)
    int schunk = (lane & 3) * 8;          // 16B chunk within the 32-ushort row

    float4v acc[4][4];
#pragma unroll
    for (int i = 0; i < 4; ++i)
#pragma unroll
        for (int j = 0; j < 4; ++j)
#pragma unroll
            for (int r = 0; r < 4; ++r) acc[i][j][r] = 0.f;

    // prologue: stage k0=0 into buffer 0
#pragma unroll
    for (int q = 0; q < 2; ++q) {
        int r = srow + q * 16;
        __builtin_amdgcn_global_load_lds(
            (gptr_t)(aBase + (size_t)r * CC + schunk),
            (sptr_t)(&As[0][(wave * 32 + q * 16) * 32]), 16, 0, 0);
        __builtin_amdgcn_global_load_lds(
            (gptr_t)(bBase + (size_t)r * CC + schunk),
            (sptr_t)(&Bs[0][(wave * 32 + q * 16) * 32]), 16, 0, 0);
    }

    for (int k0 = 0; k0 < CC; k0 += 32) {
        int cur = (k0 >> 5) & 1;
        __syncthreads();   // per-wave vmcnt(0) drain => buf[cur] resident for all
        if (k0 + 32 < CC) {
            int nxt = cur ^ 1;
#pragma unroll
            for (int q = 0; q < 2; ++q) {
                int r = srow + q * 16;
                __builtin_amdgcn_global_load_lds(
                    (gptr_t)(aBase + (size_t)r * CC + k0 + 32 + schunk),
                    (sptr_t)(&As[nxt][(wave * 32 + q * 16) * 32]), 16, 0, 0);
                __builtin_amdgcn_global_load_lds(
                    (gptr_t)(bBase + (size_t)r * CC + k0 + 32 + schunk),
                    (sptr_t)(&Bs[nxt][(wave * 32 + q * 16) * 32]), 16, 0, 0);
            }
        }
        short8 af[4], bf[4];
#pragma unroll
        for (int mt = 0; mt < 4; ++mt)
            af[mt] = *(const short8*)&As[cur][(wm * 64 + mt * 16 + l16) * 32 + quad * 8];
#pragma unroll
        for (int nt = 0; nt < 4; ++nt)
            bf[nt] = *(const short8*)&Bs[cur][(wn * 64 + nt * 16 + l16) * 32 + quad * 8];
#pragma unroll
        for (int mt = 0; mt < 4; ++mt)
#pragma unroll
            for (int nt = 0; nt < 4; ++nt)
                acc[mt][nt] = __builtin_amdgcn_mfma_f32_16x16x32_bf16(
                    af[mt], bf[nt], acc[mt][nt], 0, 0, 0);
    }

    // epilogue: gelu -> bf16 (pad rows get gelu(0)=0; gemm2 reads them as zeros)
#pragma unroll
    for (int mt = 0; mt < 4; ++mt) {
#pragma unroll
        for (int r = 0; r < 4; ++r) {
            int m = m0 + wm * 64 + mt * 16 + quad * 4 + r;
            unsigned short* orow = h_slab + ((size_t)e * CAP + m) * HH + n0 + wn * 64 + l16;
#pragma unroll
            for (int nt = 0; nt < 4; ++nt)
                orow[nt * 16] = f2bf(gelu_tanh(acc[mt][nt][r]));
        }
    }
}

// ---------- MFMA GEMM2: double-buffered, BK=32, split-K=4, no atomics ----------
// A: h_slab [e][CAP][HH]. B: wp_b [e][CC][HH]. Out: o_part[ks][ent][CC] fp32.
__global__ __launch_bounds__(256)
void gemm2_mfma(const unsigned short* __restrict__ h_slab,
                const unsigned short* __restrict__ wp_b,
                const int* __restrict__ counts,
                const int* __restrict__ tok_list,
                float* __restrict__ o_part) {
    int e = blockIdx.z;
    int M = counts[e * CNT_STRIDE]; if (M > CAP) M = CAP;
    int m0 = blockIdx.y * 128;
    if (m0 >= M) return;
    int n0 = (blockIdx.x >> 2) * 128;
    int ks = blockIdx.x & 3;

    __shared__ unsigned short As[2][128 * 32];
    __shared__ unsigned short Bs[2][128 * 32];

    int tid = threadIdx.x;
    int wave = tid >> 6, lane = tid & 63;
    int wm = wave >> 1, wn = wave & 1;
    int quad = lane >> 4, l16 = lane & 15;

    const unsigned short* aBase = h_slab + ((size_t)e * CAP + m0) * HH + ks * 768;
    const unsigned short* bBase = wp_b + ((size_t)e * CC + n0) * HH + ks * 768;

    int srow = wave * 32 + (lane >> 2);
    int schunk = (lane & 3) * 8;

    float4v acc[4][4];
#pragma unroll
    for (int i = 0; i < 4; ++i)
#pragma unroll
        for (int j = 0; j < 4; ++j)
#pragma unroll
            for (int r = 0; r < 4; ++r) acc[i][j][r] = 0.f;

#pragma unroll
    for (int q = 0; q < 2; ++q) {
        int r = srow + q * 16;
        __builtin_amdgcn_global_load_lds(
            (gptr_t)(aBase + (size_t)r * HH + schunk),
            (sptr_t)(&As[0][(wave * 32 + q * 16) * 32]), 16, 0, 0);
        __builtin_amdgcn_global_load_lds(
            (gptr_t)(bBase + (size_t)r * HH + schunk),
            (sptr_t)(&Bs[0][(wave * 32 + q * 16) * 32]), 16, 0, 0);
    }

    for (int k0 = 0; k0 < 768; k0 += 32) {
        int cur = (k0 >> 5) & 1;
        __syncthreads();
        if (k0 + 32 < 768) {
            int nxt = cur ^ 1;
#pragma unroll
            for (int q = 0; q < 2; ++q) {
                int r = srow + q * 16;
                __builtin_amdgcn_global_load_lds(
                    (gptr_t)(aBase + (size_t)r * HH + k0 + 32 + schunk),
                    (sptr_t)(&As[nxt][(wave * 32 + q * 16) * 32]), 16, 0, 0);
                __builtin_amdgcn_global_load_lds(
                    (gptr_t)(bBase + (size_t)r * HH + k0 + 32 + schunk),
                    (sptr_t)(&Bs[nxt][(wave * 32 + q * 16) * 32]), 16, 0, 0);
            }
        }
        short8 af[4], bf[4];
#pragma unroll
        for (int mt = 0; mt < 4; ++mt)
            af[mt] = *(const short8*)&As[cur][(wm * 64 + mt * 16 + l16) * 32 + quad * 8];
#pragma unroll
        for (int nt = 0; nt < 4; ++nt)
            bf[nt] = *(const short8*)&Bs[cur][(wn * 64 + nt * 16 + l16) * 32 + quad * 8];
#pragma unroll
        for (int mt = 0; mt < 4; ++mt)
#pragma unroll
            for (int nt = 0; nt < 4; ++nt)
                acc[mt][nt] = __builtin_amdgcn_mfma_f32_16x16x32_bf16(
                    af[mt], bf[nt], acc[mt][nt], 0, 0, 0);
    }

#pragma unroll
    for (int mt = 0; mt < 4; ++mt) {
#pragma unroll
        for (int r = 0; r < 4; ++r) {
            int m = m0 + wm * 64 + mt * 16 + quad * 4 + r;
            if (m < M) {
                int ent = tok_list[e * NTOK + m];
                float* orow = o_part + ((size_t)ks * NTOK * 2 + ent) * CC + n0 + wn * 64 + l16;
#pragma unroll
                for (int nt = 0; nt < 4; ++nt)
                    orow[nt * 16] = acc[mt][nt][r];
            }
        }
    }
}

// ---------- combine: out[t] = sum_k p_k * sum_ks o_part[ks][2t+k] ----------
__global__ void combine_kernel(const float* __restrict__ o_part,
                               const float* __restrict__ top_p,
                               float* __restrict__ out) {
    int idx = blockIdx.x * 256 + threadIdx.x;
    int t = idx / (CC / 4);
    int c = (idx % (CC / 4)) * 4;
    float p0 = top_p[2 * t], p1 = top_p[2 * t + 1];
    float4 s0 = make_float4(0.f, 0.f, 0.f, 0.f);
    float4 s1 = make_float4(0.f, 0.f, 0.f, 0.f);
#pragma unroll
    for (int ks = 0; ks < 4; ++ks) {
        const float4 a = *(const float4*)(o_part + ((size_t)ks * NTOK * 2 + 2 * t) * CC + c);
        const float4 b = *(const float4*)(o_part + ((size_t)ks * NTOK * 2 + 2 * t + 1) * CC + c);
        s0.x += a.x; s0.y += a.y; s0.z += a.z; s0.w += a.w;
        s1.x += b.x; s1.y += b.y; s1.z += b.z; s1.w += b.w;
    }
    float4 r;
    r.x = p0 * s0.x + p1 * s1.x;
    r.y = p0 * s0.y + p1 * s1.y;
    r.z = p0 * s0.z + p1 * s1.z;
    r.w = p0 * s0.w + p1 * s1.w;
    *(float4*)(out + (size_t)t * CC + c) = r;
}

// ---------- launch ----------
extern "C" void kernel_launch(void* const* d_in, const int* in_sizes, int n_in,
                              void* d_out, int out_size, void* d_ws, size_t ws_size,
                              hipStream_t stream) {
    const float* x      = (const float*)d_in[0];
    const float* w_fc   = (const float*)d_in[1];
    const float* w_proj = (const float*)d_in[2];
    const float* w_gate = (const float*)d_in[3];
    float* out = (float*)d_out;

    char* ws = (char*)d_ws;
    size_t off = 0;
    float* top_p    = (float*)(ws + off); off += NTOK * 2 * sizeof(float);
    int*   counts   = (int*)(ws + off);   off += CNT_STRIDE * NEXP * 4;   // 1 KB padded
    int*   tok_list = (int*)(ws + off);   off += (size_t)NEXP * NTOK * 4;
    off = 131072;
    unsigned short* wp_b   = (unsigned short*)(ws + off); off += (size_t)NEXP*CC*HH*2;  // 37.75 MB
    unsigned short* h_slab = (unsigned short*)(ws + off); off += (size_t)NEXP*CAP*HH*2; // 50.33 MB
    // o_part aliases [wfc_b][xg] (both dead once gemm1 completes; stream order
    // serializes). sizeof(o_part) = 4*4096*768*4 = 50,331,648 == wfc_b + xg.
    unsigned short* wfc_b  = (unsigned short*)(ws + off);
    float*          o_part = (float*)(ws + off);          off += (size_t)NEXP*HH*CC*2;  // 37.75 MB
    unsigned short* xg     = (unsigned short*)(ws + off); off += (size_t)NEXP*CAP*CC*2; // 12.58 MB

    hipMemsetAsync(counts, 0, CNT_STRIDE * NEXP * 4, stream);

    router_kernel<<<NTOK, 64, 0, stream>>>(x, w_gate, top_p, counts, tok_list);
    permute_w<<<dim3(CC / 32, HH / 32), 256, 0, stream>>>(w_fc, wfc_b, CC, HH);
    permute_w<<<dim3(HH / 32, CC / 32), 256, 0, stream>>>(w_proj, wp_b, HH, CC);
    gather_x<<<NEXP * CAP, 192, 0, stream>>>(x, counts, tok_list, xg);

    gemm1_mfma<<<dim3(HH / 128, CAP / 128, NEXP), 256, 0, stream>>>(
        xg, wfc_b, counts, h_slab);
    gemm2_mfma<<<dim3((CC / 128) * 4, CAP / 128, NEXP), 256, 0, stream>>>(
        h_slab, wp_b, counts, tok_list, o_part);
    combine_kernel<<<(NTOK * CC / 4) / 256, 256, 0, stream>>>(o_part, top_p, out);
}